// Round 1
// baseline (730.296 us; speedup 1.0000x reference)
//
#include <hip/hip_runtime.h>

#define NTOT 9216
#define NORMC 0.42044820762685725f   /* 32^-0.25 */
#define RATIO 0.08838834764831845f   /* 128^-0.5 */
#define FEPS 1e-4f

// ---------------------------------------------------------------- combine
// Wc[o][c'] = sum_c wp[o][c] * wo[c][c'] ; bc[o] = wp[o,:]@bo + bp[o]
__global__ __launch_bounds__(256) void combine_w(
    const float* __restrict__ wo, const float* __restrict__ bo,
    const float* __restrict__ wp, const float* __restrict__ bp,
    float* __restrict__ Wc, float* __restrict__ bc) {
  int o = blockIdx.x;
  int cp = threadIdx.x;
  float acc = 0.f;
  for (int c = 0; c < 256; ++c) acc += wp[o * 256 + c] * wo[c * 256 + cp];
  Wc[o * 256 + cp] = acc;
  if (cp == 0) {
    float ab = bp[o];
    for (int c = 0; c < 256; ++c) ab += wp[o * 256 + c] * bo[c];
    bc[o] = ab;
  }
}

// ---------------------------------------------------------------- qkv gemm
// Out[b][n][co] = sum_ci x[b][ci][n] * W[co][ci]   (64x64 tile, K-step 32)
__global__ __launch_bounds__(256) void qkv_gemm(
    const float* __restrict__ x, const float* __restrict__ wq,
    const float* __restrict__ wk, const float* __restrict__ wv,
    float* __restrict__ q, float* __restrict__ k, float* __restrict__ v) {
  __shared__ __align__(16) float As[32][68];  // [kk][nn]
  __shared__ __align__(16) float Ws[32][68];  // [kk][cc] (transposed on store)
  int n0 = blockIdx.x * 64;
  int co0 = blockIdx.y * 64;
  int z = blockIdx.z;
  int b = z / 3, sel = z % 3;
  const float* W = (sel == 0) ? wq : (sel == 1) ? wk : wv;
  float* Out = (sel == 0) ? q : (sel == 1) ? k : v;
  const float* xb = x + (size_t)b * 256 * NTOT;
  int t = threadIdx.x;
  int tn = t & 15, tm = t >> 4;  // tn: co quad (lanes-fast -> coalesced store), tm: n quad
  float acc[4][4] = {};
  for (int k0 = 0; k0 < 256; k0 += 32) {
    __syncthreads();
    for (int i = 0; i < 2; ++i) {
      int f = t + i * 256;
      int kk = f >> 4, nn4 = f & 15;
      float4 a4 = *(const float4*)(xb + (size_t)(k0 + kk) * NTOT + n0 + nn4 * 4);
      *(float4*)&As[kk][nn4 * 4] = a4;
    }
    for (int i = 0; i < 2; ++i) {
      int f = t + i * 256;
      int cc = f >> 3, k4 = f & 7;
      float4 w4 = *(const float4*)(W + (co0 + cc) * 256 + k0 + k4 * 4);
      Ws[k4 * 4 + 0][cc] = w4.x;
      Ws[k4 * 4 + 1][cc] = w4.y;
      Ws[k4 * 4 + 2][cc] = w4.z;
      Ws[k4 * 4 + 3][cc] = w4.w;
    }
    __syncthreads();
    for (int kk = 0; kk < 32; ++kk) {
      float4 a4 = ((const float4*)As[kk])[tm];
      float4 w4 = ((const float4*)Ws[kk])[tn];
      float a[4] = {a4.x, a4.y, a4.z, a4.w};
      float w[4] = {w4.x, w4.y, w4.z, w4.w};
      for (int i = 0; i < 4; ++i)
        for (int j = 0; j < 4; ++j) acc[i][j] += a[i] * w[j];
    }
  }
  for (int i = 0; i < 4; ++i) {
    int n = n0 + tm * 4 + i;
    float* row = Out + ((size_t)(b * NTOT + n)) * 256 + co0 + tn * 4;
    *(float4*)row = make_float4(acc[i][0], acc[i][1], acc[i][2], acc[i][3]);
  }
}

// ---------------------------------------------------------------- k max (stage 1)
// per (b,h): partial max over n-chunk of dash = NORMC * (k_row . proj[m])
__global__ __launch_bounds__(256) void kmax_kernel(
    const float* __restrict__ k, const float* __restrict__ proj,
    float* __restrict__ kmaxp) {
  __shared__ __align__(16) float k_s[64][36];
  __shared__ float red[256];
  int bh = blockIdx.y, b = bh >> 3, h = bh & 7;
  int nbase = blockIdx.x * 576;
  int t = threadIdx.x;
  int m = t & 127;
  int nb2 = t >> 7;
  float pr[32];
  for (int d = 0; d < 32; ++d) pr[d] = proj[m * 32 + d];
  float lmax = -1e30f;
  for (int tile = 0; tile < 9; ++tile) {
    int n0 = nbase + tile * 64;
    __syncthreads();
    for (int i = 0; i < 2; ++i) {
      int f = t + i * 256;
      int nn = f >> 3, d4 = f & 7;
      *(float4*)&k_s[nn][d4 * 4] =
          *(const float4*)(k + ((size_t)(b * NTOT + n0 + nn)) * 256 + h * 32 + d4 * 4);
    }
    __syncthreads();
    for (int i = 0; i < 32; ++i) {
      int nn = nb2 + 2 * i;
      const float4* kr = (const float4*)k_s[nn];
      float dot = 0.f;
      for (int d4 = 0; d4 < 8; ++d4) {
        float4 kv = kr[d4];
        dot += kv.x * pr[4 * d4] + kv.y * pr[4 * d4 + 1] + kv.z * pr[4 * d4 + 2] +
               kv.w * pr[4 * d4 + 3];
      }
      lmax = fmaxf(lmax, dot);
    }
  }
  red[t] = lmax;
  __syncthreads();
  for (int s = 128; s >= 1; s >>= 1) {
    if (t < s) red[t] = fmaxf(red[t], red[t + s]);
    __syncthreads();
  }
  if (t == 0) kmaxp[bh * 16 + blockIdx.x] = red[0] * NORMC;
}

// ---------------------------------------------------------------- ctx + ksum
// ctx[b,h,m,d] += sum_n kp[n][m]*v[n][d];  ksum[b,h,m] += sum_n kp[n][m]
__global__ __launch_bounds__(256) void ctx_kernel(
    const float* __restrict__ k, const float* __restrict__ v,
    const float* __restrict__ proj, const float* __restrict__ kmaxp,
    float* __restrict__ ctx, float* __restrict__ ksum) {
  __shared__ __align__(16) float k_s[64][36];
  __shared__ __align__(16) float v_s[64][36];
  __shared__ float kp_s[64][129];
  __shared__ float diag_s[64];
  __shared__ float kmax_sh;
  int bh = blockIdx.y, b = bh >> 3, h = bh & 7;
  int nbase = blockIdx.x * 576;
  int t = threadIdx.x;
  int m = t & 127;
  int nb2 = t >> 7;
  float pr[32];
  for (int d = 0; d < 32; ++d) pr[d] = proj[m * 32 + d];
  if (t == 0) {
    float mx = -1e30f;
    for (int i = 0; i < 16; ++i) mx = fmaxf(mx, kmaxp[bh * 16 + i]);
    kmax_sh = mx;
  }
  __syncthreads();
  float kmax = kmax_sh;
  int tm = t & 31, td = t >> 5;
  float acc[4][4] = {};
  float ksacc[4] = {};
  for (int tile = 0; tile < 9; ++tile) {
    int n0 = nbase + tile * 64;
    __syncthreads();
    for (int i = 0; i < 2; ++i) {
      int f = t + i * 256;
      int nn = f >> 3, d4 = f & 7;
      size_t base = ((size_t)(b * NTOT + n0 + nn)) * 256 + h * 32 + d4 * 4;
      *(float4*)&k_s[nn][d4 * 4] = *(const float4*)(k + base);
      *(float4*)&v_s[nn][d4 * 4] = *(const float4*)(v + base);
    }
    __syncthreads();
    if (t < 64) {
      const float4* kr = (const float4*)k_s[t];
      float s = 0.f;
      for (int d4 = 0; d4 < 8; ++d4) {
        float4 kv = kr[d4];
        s += kv.x * kv.x + kv.y * kv.y + kv.z * kv.z + kv.w * kv.w;
      }
      diag_s[t] = s * (0.5f * NORMC * NORMC);
    }
    __syncthreads();
    for (int i = 0; i < 32; ++i) {
      int nn = nb2 + 2 * i;
      const float4* kr = (const float4*)k_s[nn];
      float dot = 0.f;
      for (int d4 = 0; d4 < 8; ++d4) {
        float4 kv = kr[d4];
        dot += kv.x * pr[4 * d4] + kv.y * pr[4 * d4 + 1] + kv.z * pr[4 * d4 + 2] +
               kv.w * pr[4 * d4 + 3];
      }
      kp_s[nn][m] = RATIO * (__expf(NORMC * dot - diag_s[nn] - kmax) + FEPS);
    }
    __syncthreads();
    for (int n = 0; n < 64; ++n) {
      float a[4];
      for (int i = 0; i < 4; ++i) a[i] = kp_s[n][tm + 32 * i];
      float4 vv4 = ((const float4*)v_s[n])[td];
      float vv[4] = {vv4.x, vv4.y, vv4.z, vv4.w};
      for (int i = 0; i < 4; ++i)
        for (int j = 0; j < 4; ++j) acc[i][j] += a[i] * vv[j];
      if (td == 0)
        for (int i = 0; i < 4; ++i) ksacc[i] += a[i];
    }
  }
  float* cb = ctx + (size_t)bh * 4096;
  for (int i = 0; i < 4; ++i)
    for (int j = 0; j < 4; ++j)
      atomicAdd(&cb[(tm + 32 * i) * 32 + td * 4 + j], acc[i][j]);
  if (td == 0)
    for (int i = 0; i < 4; ++i) atomicAdd(&ksum[bh * 128 + tm + 32 * i], ksacc[i]);
}

// ---------------------------------------------------------------- q side + attention out
__global__ __launch_bounds__(256) void attn_kernel(
    const float* __restrict__ q, const float* __restrict__ proj,
    const float* __restrict__ ctx, const float* __restrict__ ksum,
    float* __restrict__ attn) {
  __shared__ __align__(16) float q_s[64][36];
  __shared__ __align__(16) float ctx_s[128][36];
  __shared__ float dash_s[64][129];
  __shared__ float ksum_s[128];
  __shared__ float diag_s[64], rmax_s[64], dinv_s[64];
  int bh = blockIdx.y, b = bh >> 3, h = bh & 7;
  int n0 = blockIdx.x * 64;
  int t = threadIdx.x;
  int m = t & 127;
  int nb2 = t >> 7;
  float pr[32];
  for (int d = 0; d < 32; ++d) pr[d] = proj[m * 32 + d];
  const float* cb = ctx + (size_t)bh * 4096;
  for (int i = 0; i < 4; ++i) {
    int f = t + i * 256;  // 1024 float4s of ctx
    int mm = f >> 3, d4 = f & 7;
    *(float4*)&ctx_s[mm][d4 * 4] = *(const float4*)(cb + mm * 32 + d4 * 4);
  }
  if (t < 128) ksum_s[t] = ksum[bh * 128 + t];
  for (int i = 0; i < 2; ++i) {
    int f = t + i * 256;
    int nn = f >> 3, d4 = f & 7;
    *(float4*)&q_s[nn][d4 * 4] =
        *(const float4*)(q + ((size_t)(b * NTOT + n0 + nn)) * 256 + h * 32 + d4 * 4);
  }
  __syncthreads();
  if (t < 64) {
    const float4* qr = (const float4*)q_s[t];
    float s = 0.f;
    for (int d4 = 0; d4 < 8; ++d4) {
      float4 qv = qr[d4];
      s += qv.x * qv.x + qv.y * qv.y + qv.z * qv.z + qv.w * qv.w;
    }
    diag_s[t] = s * (0.5f * NORMC * NORMC);
  }
  for (int i = 0; i < 32; ++i) {
    int nn = nb2 + 2 * i;
    const float4* qr = (const float4*)q_s[nn];
    float dot = 0.f;
    for (int d4 = 0; d4 < 8; ++d4) {
      float4 qv = qr[d4];
      dot += qv.x * pr[4 * d4] + qv.y * pr[4 * d4 + 1] + qv.z * pr[4 * d4 + 2] +
             qv.w * pr[4 * d4 + 3];
    }
    dash_s[nn][m] = NORMC * dot;
  }
  __syncthreads();
  if (t < 64) {
    float mx = -1e30f;
    for (int mm = 0; mm < 128; ++mm) mx = fmaxf(mx, dash_s[t][mm]);
    rmax_s[t] = mx;
  }
  __syncthreads();
  for (int i = 0; i < 32; ++i) {
    int nn = nb2 + 2 * i;
    dash_s[nn][m] = RATIO * (__expf(dash_s[nn][m] - diag_s[nn] - rmax_s[nn]) + FEPS);
  }
  __syncthreads();
  if (t < 64) {
    float s = 0.f;
    for (int mm = 0; mm < 128; ++mm) s += dash_s[t][mm] * ksum_s[mm];
    dinv_s[t] = 1.f / s;
  }
  __syncthreads();
  int d0 = (t & 3) * 8, nn = t >> 2;
  float acc[8] = {};
  for (int mm = 0; mm < 128; ++mm) {
    float qv = dash_s[nn][mm];
    float4 c0 = ((const float4*)ctx_s[mm])[(t & 3) * 2];
    float4 c1 = ((const float4*)ctx_s[mm])[(t & 3) * 2 + 1];
    acc[0] += qv * c0.x; acc[1] += qv * c0.y; acc[2] += qv * c0.z; acc[3] += qv * c0.w;
    acc[4] += qv * c1.x; acc[5] += qv * c1.y; acc[6] += qv * c1.z; acc[7] += qv * c1.w;
  }
  float di = dinv_s[nn];
  float* orow = attn + ((size_t)(b * NTOT + n0 + nn)) * 256 + h * 32 + d0;
  *(float4*)orow = make_float4(acc[0] * di, acc[1] * di, acc[2] * di, acc[3] * di);
  *(float4*)(orow + 4) = make_float4(acc[4] * di, acc[5] * di, acc[6] * di, acc[7] * di);
}

// ---------------------------------------------------------------- combined output gemm
// out[b][o][n] = sum_c attn[b][n][c] * Wc[o][c] + bc[o]
__global__ __launch_bounds__(256) void out_gemm(
    const float* __restrict__ attn, const float* __restrict__ Wc,
    const float* __restrict__ bc, float* __restrict__ out) {
  __shared__ __align__(16) float As[32][68];  // [kk][nn]
  __shared__ __align__(16) float Ws[32][68];  // [kk][oo]
  int n0 = blockIdx.x * 64;
  int o0 = blockIdx.y * 64;
  int b = blockIdx.z;
  int t = threadIdx.x;
  int tm = t & 15, tn = t >> 4;  // tm: n quad (lanes-fast -> coalesced store), tn: o quad
  float acc[4][4] = {};
  for (int k0 = 0; k0 < 256; k0 += 32) {
    __syncthreads();
    for (int i = 0; i < 2; ++i) {
      int f = t + i * 256;
      int nn = f >> 3, c4 = f & 7;
      float4 a4 =
          *(const float4*)(attn + ((size_t)(b * NTOT + n0 + nn)) * 256 + k0 + c4 * 4);
      As[c4 * 4 + 0][nn] = a4.x;
      As[c4 * 4 + 1][nn] = a4.y;
      As[c4 * 4 + 2][nn] = a4.z;
      As[c4 * 4 + 3][nn] = a4.w;
    }
    for (int i = 0; i < 2; ++i) {
      int f = t + i * 256;
      int cc = f >> 3, k4 = f & 7;
      float4 w4 = *(const float4*)(Wc + (o0 + cc) * 256 + k0 + k4 * 4);
      Ws[k4 * 4 + 0][cc] = w4.x;
      Ws[k4 * 4 + 1][cc] = w4.y;
      Ws[k4 * 4 + 2][cc] = w4.z;
      Ws[k4 * 4 + 3][cc] = w4.w;
    }
    __syncthreads();
    for (int kk = 0; kk < 32; ++kk) {
      float4 a4 = ((const float4*)As[kk])[tm];
      float4 w4 = ((const float4*)Ws[kk])[tn];
      float a[4] = {a4.x, a4.y, a4.z, a4.w};
      float w[4] = {w4.x, w4.y, w4.z, w4.w};
      for (int i = 0; i < 4; ++i)
        for (int j = 0; j < 4; ++j) acc[i][j] += a[i] * w[j];
    }
  }
  for (int j = 0; j < 4; ++j) {
    int o = o0 + tn * 4 + j;
    float bias = bc[o];
    float* row = out + ((size_t)(b * 256 + o)) * NTOT + n0 + tm * 4;
    *(float4*)row = make_float4(acc[0][j] + bias, acc[1][j] + bias,
                                acc[2][j] + bias, acc[3][j] + bias);
  }
}

// ---------------------------------------------------------------- launch
extern "C" void kernel_launch(void* const* d_in, const int* in_sizes, int n_in,
                              void* d_out, int out_size, void* d_ws, size_t ws_size,
                              hipStream_t stream) {
  const float* x = (const float*)d_in[0];
  const float* wq = (const float*)d_in[1];
  const float* wk = (const float*)d_in[2];
  const float* wv = (const float*)d_in[3];
  const float* wo = (const float*)d_in[4];
  const float* bo = (const float*)d_in[5];
  const float* proj = (const float*)d_in[6];
  const float* wp = (const float*)d_in[7];
  const float* bp = (const float*)d_in[8];
  float* out = (float*)d_out;
  float* ws = (float*)d_ws;

  const size_t tens = (size_t)4 * NTOT * 256;  // 9,437,184 floats
  float* q = ws;
  float* k = q + tens;
  float* v = k + tens;  // reused as attn output after ctx_kernel
  float* ctx = v + tens;               // 32*4096
  float* ksum = ctx + 32 * 4096;       // 32*128
  float* kmaxp = ksum + 32 * 128;      // 512
  float* Wc = kmaxp + 512;             // 65536
  float* bc = Wc + 65536;              // 256

  hipMemsetAsync(ctx, 0, (32 * 4096 + 32 * 128) * sizeof(float), stream);
  combine_w<<<256, 256, 0, stream>>>(wo, bo, wp, bp, Wc, bc);
  qkv_gemm<<<dim3(144, 4, 12), 256, 0, stream>>>(x, wq, wk, wv, q, k, v);
  kmax_kernel<<<dim3(16, 32), 256, 0, stream>>>(k, proj, kmaxp);
  ctx_kernel<<<dim3(16, 32), 256, 0, stream>>>(k, v, proj, kmaxp, ctx, ksum);
  attn_kernel<<<dim3(144, 32), 256, 0, stream>>>(q, proj, ctx, ksum, v);
  out_gemm<<<dim3(144, 4, 4), 256, 0, stream>>>(v, Wc, bc, out);
}

// Round 2
// 561.078 us; speedup vs baseline: 1.3016x; 1.3016x over previous
//
#include <hip/hip_runtime.h>

#define NTOT 9216
#define NORMC 0.42044820762685725f   /* 32^-0.25 */
#define RATIO 0.08838834764831845f   /* 128^-0.5 */
#define FEPS 1e-4f

typedef _Float16 h8 __attribute__((ext_vector_type(8)));
typedef float f4 __attribute__((ext_vector_type(4)));

// ---------------------------------------------------------------- weight convert
__global__ __launch_bounds__(256) void conv_w(
    const float* __restrict__ wq, const float* __restrict__ wk,
    const float* __restrict__ wv, _Float16* __restrict__ Wall) {
  int r = blockIdx.x, t = threadIdx.x;
  const float* src = (r < 256) ? wq + (size_t)r * 256
                   : (r < 512) ? wk + (size_t)(r - 256) * 256
                               : wv + (size_t)(r - 512) * 256;
  Wall[(size_t)r * 256 + t] = (_Float16)src[t];
}

// ---------------------------------------------------------------- combine
// Wc[o][c'] = sum_c wp[o][c] * wo[c][c'] (fp16) ; bc[o] = wp[o,:]@bo + bp[o]
__global__ __launch_bounds__(256) void combine_w(
    const float* __restrict__ wo, const float* __restrict__ bo,
    const float* __restrict__ wp, const float* __restrict__ bp,
    _Float16* __restrict__ Wc, float* __restrict__ bc) {
  int o = blockIdx.x;
  int cp = threadIdx.x;
  float acc = 0.f;
  for (int c = 0; c < 256; ++c) acc += wp[o * 256 + c] * wo[c * 256 + cp];
  Wc[o * 256 + cp] = (_Float16)acc;
  if (cp == 0) {
    float ab = bp[o];
    for (int c = 0; c < 256; ++c) ab += wp[o * 256 + c] * bo[c];
    bc[o] = ab;
  }
}

// ---------------------------------------------------------------- x transpose fp32 [b][c][n] -> fp16 [b*n][c]
__global__ __launch_bounds__(256) void prep_xT(
    const float* __restrict__ x, _Float16* __restrict__ xT) {
  __shared__ float T_s[64][65];
  int n0 = blockIdx.x * 64, c0 = blockIdx.y * 64, b = blockIdx.z;
  int t = threadIdx.x;
  for (int i = 0; i < 4; ++i) {
    int f = t + i * 256;
    int cc = f >> 4, n4 = f & 15;
    float4 a = *(const float4*)(x + ((size_t)(b * 256 + c0 + cc)) * NTOT + n0 + n4 * 4);
    T_s[cc][n4 * 4 + 0] = a.x;
    T_s[cc][n4 * 4 + 1] = a.y;
    T_s[cc][n4 * 4 + 2] = a.z;
    T_s[cc][n4 * 4 + 3] = a.w;
  }
  __syncthreads();
  for (int i = 0; i < 2; ++i) {
    int f = t + i * 256;
    int nn = f >> 3, c8 = f & 7;
    h8 hv;
    for (int j = 0; j < 8; ++j) hv[j] = (_Float16)T_s[c8 * 8 + j][nn];
    *(h8*)(xT + ((size_t)(b * NTOT + n0 + nn)) * 256 + c0 + c8 * 8) = hv;
  }
}

// ---------------------------------------------------------------- qkv MFMA gemm
// Out_sel[row n][col co] = sum_c xT[n][c] * W[co][c], fp16 in/out, fp32 acc
__global__ __launch_bounds__(256) void qkv_mfma(
    const _Float16* __restrict__ xT, const _Float16* __restrict__ Wall,
    _Float16* __restrict__ q, _Float16* __restrict__ k, _Float16* __restrict__ v) {
  __shared__ __align__(16) _Float16 A_s[128 * 32];  // [n][c]  rows of 64B
  __shared__ __align__(16) _Float16 B_s[256 * 32];  // [co][c] rows of 64B
  int n0 = blockIdx.x * 128;
  int sel = blockIdx.y;
  _Float16* Out = (sel == 0) ? q : (sel == 1) ? k : v;
  const _Float16* Wb = Wall + (size_t)sel * 256 * 256;
  int t = threadIdx.x;
  int wave = t >> 6, lane = t & 63;
  int wm = (wave & 1) * 64, wn = (wave >> 1) * 128;
  int lm = lane & 15, lg = lane >> 4;
  f4 acc[4][8] = {};
  for (int kt = 0; kt < 8; ++kt) {
    int c0 = kt * 32;
    __syncthreads();
    {
      int row = t >> 2, ch = t & 3;
      const _Float16* g = xT + (size_t)(n0 + row) * 256 + c0 + ch * 8;
      *(h8*)&A_s[row * 32 + ch * 8] = *(const h8*)g;
      *(h8*)&A_s[(row + 64) * 32 + ch * 8] = *(const h8*)(g + 64 * 256);
#pragma unroll
      for (int i = 0; i < 4; ++i) {
        const _Float16* gw = Wb + (size_t)(row + i * 64) * 256 + c0 + ch * 8;
        *(h8*)&B_s[(row + i * 64) * 32 + ch * 8] = *(const h8*)gw;
      }
    }
    __syncthreads();
    h8 a[4], b[8];
#pragma unroll
    for (int mi = 0; mi < 4; ++mi)
      a[mi] = *(const h8*)&A_s[(wm + mi * 16 + lm) * 32 + lg * 8];
#pragma unroll
    for (int ni = 0; ni < 8; ++ni)
      b[ni] = *(const h8*)&B_s[(wn + ni * 16 + lm) * 32 + lg * 8];
#pragma unroll
    for (int mi = 0; mi < 4; ++mi)
#pragma unroll
      for (int ni = 0; ni < 8; ++ni)
        acc[mi][ni] = __builtin_amdgcn_mfma_f32_16x16x32_f16(a[mi], b[ni], acc[mi][ni], 0, 0, 0);
  }
#pragma unroll
  for (int mi = 0; mi < 4; ++mi)
#pragma unroll
    for (int ni = 0; ni < 8; ++ni)
#pragma unroll
      for (int r = 0; r < 4; ++r) {
        int row = n0 + wm + mi * 16 + lg * 4 + r;
        int col = wn + ni * 16 + lm;
        Out[(size_t)row * 256 + col] = (_Float16)acc[mi][ni][r];
      }
}

// ---------------------------------------------------------------- k max (stage 1)
__global__ __launch_bounds__(256) void kmax_kernel(
    const _Float16* __restrict__ k, const float* __restrict__ proj,
    float* __restrict__ kmaxp) {
  __shared__ __align__(16) float k_s[64][36];
  __shared__ float red[256];
  int bh = blockIdx.y, b = bh >> 3, h = bh & 7;
  int nbase = blockIdx.x * 576;
  int t = threadIdx.x;
  int m = t & 127;
  int nb2 = t >> 7;
  float pr[32];
  for (int d = 0; d < 32; ++d) pr[d] = proj[m * 32 + d];
  float lmax = -1e30f;
  for (int tile = 0; tile < 9; ++tile) {
    int n0 = nbase + tile * 64;
    __syncthreads();
    {
      int nn = t >> 2, dc = t & 3;
      h8 kv = *(const h8*)(k + ((size_t)(b * NTOT + n0 + nn)) * 256 + h * 32 + dc * 8);
      *(float4*)&k_s[nn][dc * 8] = make_float4(kv[0], kv[1], kv[2], kv[3]);
      *(float4*)&k_s[nn][dc * 8 + 4] = make_float4(kv[4], kv[5], kv[6], kv[7]);
    }
    __syncthreads();
    for (int i = 0; i < 32; ++i) {
      int nn = nb2 + 2 * i;
      const float4* kr = (const float4*)k_s[nn];
      float dot = 0.f;
      for (int d4 = 0; d4 < 8; ++d4) {
        float4 kv = kr[d4];
        dot += kv.x * pr[4 * d4] + kv.y * pr[4 * d4 + 1] + kv.z * pr[4 * d4 + 2] +
               kv.w * pr[4 * d4 + 3];
      }
      lmax = fmaxf(lmax, dot);
    }
  }
  red[t] = lmax;
  __syncthreads();
  for (int s = 128; s >= 1; s >>= 1) {
    if (t < s) red[t] = fmaxf(red[t], red[t + s]);
    __syncthreads();
  }
  if (t == 0) kmaxp[bh * 16 + blockIdx.x] = red[0] * NORMC;
}

// ---------------------------------------------------------------- ctx + ksum
__global__ __launch_bounds__(256) void ctx_kernel(
    const _Float16* __restrict__ k, const _Float16* __restrict__ v,
    const float* __restrict__ proj, const float* __restrict__ kmaxp,
    float* __restrict__ ctx, float* __restrict__ ksum) {
  __shared__ __align__(16) float k_s[64][36];
  __shared__ __align__(16) float v_s[64][36];
  __shared__ float kp_s[64][129];
  __shared__ float diag_s[64];
  __shared__ float kmax_sh;
  int bh = blockIdx.y, b = bh >> 3, h = bh & 7;
  int nbase = blockIdx.x * 576;
  int t = threadIdx.x;
  int m = t & 127;
  int nb2 = t >> 7;
  float pr[32];
  for (int d = 0; d < 32; ++d) pr[d] = proj[m * 32 + d];
  if (t == 0) {
    float mx = -1e30f;
    for (int i = 0; i < 16; ++i) mx = fmaxf(mx, kmaxp[bh * 16 + i]);
    kmax_sh = mx;
  }
  __syncthreads();
  float kmax = kmax_sh;
  int tm = t & 31, td = t >> 5;
  float acc[4][4] = {};
  float ksacc[4] = {};
  for (int tile = 0; tile < 9; ++tile) {
    int n0 = nbase + tile * 64;
    __syncthreads();
    {
      int nn = t >> 2, dc = t & 3;
      size_t base = ((size_t)(b * NTOT + n0 + nn)) * 256 + h * 32 + dc * 8;
      h8 kv = *(const h8*)(k + base);
      h8 vv = *(const h8*)(v + base);
      *(float4*)&k_s[nn][dc * 8] = make_float4(kv[0], kv[1], kv[2], kv[3]);
      *(float4*)&k_s[nn][dc * 8 + 4] = make_float4(kv[4], kv[5], kv[6], kv[7]);
      *(float4*)&v_s[nn][dc * 8] = make_float4(vv[0], vv[1], vv[2], vv[3]);
      *(float4*)&v_s[nn][dc * 8 + 4] = make_float4(vv[4], vv[5], vv[6], vv[7]);
    }
    __syncthreads();
    if (t < 64) {
      const float4* kr = (const float4*)k_s[t];
      float s = 0.f;
      for (int d4 = 0; d4 < 8; ++d4) {
        float4 kv = kr[d4];
        s += kv.x * kv.x + kv.y * kv.y + kv.z * kv.z + kv.w * kv.w;
      }
      diag_s[t] = s * (0.5f * NORMC * NORMC);
    }
    __syncthreads();
    for (int i = 0; i < 32; ++i) {
      int nn = nb2 + 2 * i;
      const float4* kr = (const float4*)k_s[nn];
      float dot = 0.f;
      for (int d4 = 0; d4 < 8; ++d4) {
        float4 kv = kr[d4];
        dot += kv.x * pr[4 * d4] + kv.y * pr[4 * d4 + 1] + kv.z * pr[4 * d4 + 2] +
               kv.w * pr[4 * d4 + 3];
      }
      kp_s[nn][m] = RATIO * (__expf(NORMC * dot - diag_s[nn] - kmax) + FEPS);
    }
    __syncthreads();
    for (int n = 0; n < 64; ++n) {
      float a[4];
      for (int i = 0; i < 4; ++i) a[i] = kp_s[n][tm + 32 * i];
      float4 vv4 = ((const float4*)v_s[n])[td];
      float vv[4] = {vv4.x, vv4.y, vv4.z, vv4.w};
      for (int i = 0; i < 4; ++i)
        for (int j = 0; j < 4; ++j) acc[i][j] += a[i] * vv[j];
      if (td == 0)
        for (int i = 0; i < 4; ++i) ksacc[i] += a[i];
    }
  }
  float* cb = ctx + (size_t)bh * 4096;
  for (int i = 0; i < 4; ++i)
    for (int j = 0; j < 4; ++j)
      atomicAdd(&cb[(tm + 32 * i) * 32 + td * 4 + j], acc[i][j]);
  if (td == 0)
    for (int i = 0; i < 4; ++i) atomicAdd(&ksum[bh * 128 + tm + 32 * i], ksacc[i]);
}

// ---------------------------------------------------------------- q side + attention out (fp16 out)
__global__ __launch_bounds__(256) void attn_kernel(
    const _Float16* __restrict__ q, const float* __restrict__ proj,
    const float* __restrict__ ctx, const float* __restrict__ ksum,
    _Float16* __restrict__ attn) {
  __shared__ __align__(16) float q_s[64][36];
  __shared__ __align__(16) float ctx_s[128][36];
  __shared__ float dash_s[64][129];
  __shared__ float ksum_s[128];
  __shared__ float diag_s[64], rmax_s[64], dinv_s[64];
  int bh = blockIdx.y, b = bh >> 3, h = bh & 7;
  int n0 = blockIdx.x * 64;
  int t = threadIdx.x;
  int m = t & 127;
  int nb2 = t >> 7;
  float pr[32];
  for (int d = 0; d < 32; ++d) pr[d] = proj[m * 32 + d];
  const float* cb = ctx + (size_t)bh * 4096;
  for (int i = 0; i < 4; ++i) {
    int f = t + i * 256;
    int mm = f >> 3, d4 = f & 7;
    *(float4*)&ctx_s[mm][d4 * 4] = *(const float4*)(cb + mm * 32 + d4 * 4);
  }
  if (t < 128) ksum_s[t] = ksum[bh * 128 + t];
  {
    int nn = t >> 2, dc = t & 3;
    h8 qv = *(const h8*)(q + ((size_t)(b * NTOT + n0 + nn)) * 256 + h * 32 + dc * 8);
    *(float4*)&q_s[nn][dc * 8] = make_float4(qv[0], qv[1], qv[2], qv[3]);
    *(float4*)&q_s[nn][dc * 8 + 4] = make_float4(qv[4], qv[5], qv[6], qv[7]);
  }
  __syncthreads();
  if (t < 64) {
    const float4* qr = (const float4*)q_s[t];
    float s = 0.f;
    for (int d4 = 0; d4 < 8; ++d4) {
      float4 qv = qr[d4];
      s += qv.x * qv.x + qv.y * qv.y + qv.z * qv.z + qv.w * qv.w;
    }
    diag_s[t] = s * (0.5f * NORMC * NORMC);
  }
  for (int i = 0; i < 32; ++i) {
    int nn = nb2 + 2 * i;
    const float4* qr = (const float4*)q_s[nn];
    float dot = 0.f;
    for (int d4 = 0; d4 < 8; ++d4) {
      float4 qv = qr[d4];
      dot += qv.x * pr[4 * d4] + qv.y * pr[4 * d4 + 1] + qv.z * pr[4 * d4 + 2] +
             qv.w * pr[4 * d4 + 3];
    }
    dash_s[nn][m] = NORMC * dot;
  }
  __syncthreads();
  if (t < 64) {
    float mx = -1e30f;
    for (int mm = 0; mm < 128; ++mm) mx = fmaxf(mx, dash_s[t][mm]);
    rmax_s[t] = mx;
  }
  __syncthreads();
  for (int i = 0; i < 32; ++i) {
    int nn = nb2 + 2 * i;
    dash_s[nn][m] = RATIO * (__expf(dash_s[nn][m] - diag_s[nn] - rmax_s[nn]) + FEPS);
  }
  __syncthreads();
  if (t < 64) {
    float s = 0.f;
    for (int mm = 0; mm < 128; ++mm) s += dash_s[t][mm] * ksum_s[mm];
    dinv_s[t] = 1.f / s;
  }
  __syncthreads();
  int d0 = (t & 3) * 8, nn = t >> 2;
  float acc[8] = {};
  for (int mm = 0; mm < 128; ++mm) {
    float qv = dash_s[nn][mm];
    float4 c0 = ((const float4*)ctx_s[mm])[(t & 3) * 2];
    float4 c1 = ((const float4*)ctx_s[mm])[(t & 3) * 2 + 1];
    acc[0] += qv * c0.x; acc[1] += qv * c0.y; acc[2] += qv * c0.z; acc[3] += qv * c0.w;
    acc[4] += qv * c1.x; acc[5] += qv * c1.y; acc[6] += qv * c1.z; acc[7] += qv * c1.w;
  }
  float di = dinv_s[nn];
  h8 ov;
  for (int j = 0; j < 8; ++j) ov[j] = (_Float16)(acc[j] * di);
  *(h8*)(attn + ((size_t)(b * NTOT + n0 + nn)) * 256 + h * 32 + d0) = ov;
}

// ---------------------------------------------------------------- output MFMA gemm
// out[b][o][n] = sum_c Wc[o][c] * attn[n][c] + bc[o]
__global__ __launch_bounds__(256) void out_mfma(
    const _Float16* __restrict__ Wc, const _Float16* __restrict__ attn,
    const float* __restrict__ bc, float* __restrict__ out) {
  __shared__ __align__(16) _Float16 A_s[128 * 32];  // [o][c]
  __shared__ __align__(16) _Float16 B_s[256 * 32];  // [n][c]
  int n0 = blockIdx.x * 256;   // global row over 4*9216
  int o0 = blockIdx.y * 128;
  int b = n0 / NTOT;
  int nb0 = n0 - b * NTOT;
  int t = threadIdx.x;
  int wave = t >> 6, lane = t & 63;
  int wm = (wave & 1) * 64, wn = (wave >> 1) * 128;
  int lm = lane & 15, lg = lane >> 4;
  f4 acc[4][8] = {};
  for (int kt = 0; kt < 8; ++kt) {
    int c0 = kt * 32;
    __syncthreads();
    {
      int row = t >> 2, ch = t & 3;
      const _Float16* ga = Wc + (size_t)(o0 + row) * 256 + c0 + ch * 8;
      *(h8*)&A_s[row * 32 + ch * 8] = *(const h8*)ga;
      *(h8*)&A_s[(row + 64) * 32 + ch * 8] = *(const h8*)(ga + 64 * 256);
#pragma unroll
      for (int i = 0; i < 4; ++i) {
        const _Float16* gb = attn + (size_t)(n0 + row + i * 64) * 256 + c0 + ch * 8;
        *(h8*)&B_s[(row + i * 64) * 32 + ch * 8] = *(const h8*)gb;
      }
    }
    __syncthreads();
    h8 a[4], b8[8];
#pragma unroll
    for (int mi = 0; mi < 4; ++mi)
      a[mi] = *(const h8*)&A_s[(wm + mi * 16 + lm) * 32 + lg * 8];
#pragma unroll
    for (int ni = 0; ni < 8; ++ni)
      b8[ni] = *(const h8*)&B_s[(wn + ni * 16 + lm) * 32 + lg * 8];
#pragma unroll
    for (int mi = 0; mi < 4; ++mi)
#pragma unroll
      for (int ni = 0; ni < 8; ++ni)
        acc[mi][ni] = __builtin_amdgcn_mfma_f32_16x16x32_f16(a[mi], b8[ni], acc[mi][ni], 0, 0, 0);
  }
  float bias[4][4];
#pragma unroll
  for (int mi = 0; mi < 4; ++mi)
#pragma unroll
    for (int r = 0; r < 4; ++r)
      bias[mi][r] = bc[o0 + wm + mi * 16 + lg * 4 + r];
#pragma unroll
  for (int mi = 0; mi < 4; ++mi)
#pragma unroll
    for (int ni = 0; ni < 8; ++ni)
#pragma unroll
      for (int r = 0; r < 4; ++r) {
        int o = o0 + wm + mi * 16 + lg * 4 + r;
        int n = nb0 + wn + ni * 16 + lm;
        out[((size_t)(b * 256 + o)) * NTOT + n] = acc[mi][ni][r] + bias[mi][r];
      }
}

// ---------------------------------------------------------------- launch
extern "C" void kernel_launch(void* const* d_in, const int* in_sizes, int n_in,
                              void* d_out, int out_size, void* d_ws, size_t ws_size,
                              hipStream_t stream) {
  const float* x = (const float*)d_in[0];
  const float* wq = (const float*)d_in[1];
  const float* wk = (const float*)d_in[2];
  const float* wv = (const float*)d_in[3];
  const float* wo = (const float*)d_in[4];
  const float* bo = (const float*)d_in[5];
  const float* proj = (const float*)d_in[6];
  const float* wp = (const float*)d_in[7];
  const float* bp = (const float*)d_in[8];
  float* out = (float*)d_out;

  float* ctx = (float*)d_ws;             // 131072
  float* ksum = ctx + 131072;            // 4096
  float* kmaxp = ksum + 4096;            // 512
  float* bc = kmaxp + 512;               // 256
  _Float16* hb = (_Float16*)(bc + 256);
  const size_t THALF = (size_t)4 * NTOT * 256;  // 9,437,184
  _Float16* q_h = hb;
  _Float16* k_h = q_h + THALF;
  _Float16* v_h = k_h + THALF;
  _Float16* xT = v_h + THALF;   // reused as attn_h after qkv_mfma
  _Float16* Wall = xT + THALF;  // 768*256
  _Float16* Wc = Wall + 768 * 256;  // 256*256

  hipMemsetAsync(ctx, 0, (131072 + 4096) * sizeof(float), stream);
  conv_w<<<768, 256, 0, stream>>>(wq, wk, wv, Wall);
  combine_w<<<256, 256, 0, stream>>>(wo, bo, wp, bp, Wc, bc);
  prep_xT<<<dim3(144, 4, 4), 256, 0, stream>>>(x, xT);
  qkv_mfma<<<dim3(288, 3), 256, 0, stream>>>(xT, Wall, q_h, k_h, v_h);
  kmax_kernel<<<dim3(16, 32), 256, 0, stream>>>(k_h, proj, kmaxp);
  ctx_kernel<<<dim3(16, 32), 256, 0, stream>>>(k_h, v_h, proj, kmaxp, ctx, ksum);
  attn_kernel<<<dim3(144, 32), 256, 0, stream>>>(q_h, proj, ctx, ksum, xT);
  out_mfma<<<dim3(144, 2), 256, 0, stream>>>(Wc, xT, bc, out);
}

// Round 3
// 273.239 us; speedup vs baseline: 2.6727x; 2.0534x over previous
//
#include <hip/hip_runtime.h>

#define NTOT 9216
#define NORMC 0.42044820762685725f   /* 32^-0.25 */
#define RATIO 0.08838834764831845f   /* 128^-0.5 */
#define FEPS 1e-4f

typedef _Float16 h8 __attribute__((ext_vector_type(8)));
typedef float f4 __attribute__((ext_vector_type(4)));

// ---------------------------------------------------------------- weight/proj convert
__global__ __launch_bounds__(256) void conv_w(
    const float* __restrict__ wq, const float* __restrict__ wk,
    const float* __restrict__ wv, const float* __restrict__ proj,
    _Float16* __restrict__ Wall, _Float16* __restrict__ projh) {
  int r = blockIdx.x, t = threadIdx.x;
  if (r < 768) {
    const float* src = (r < 256) ? wq + (size_t)r * 256
                     : (r < 512) ? wk + (size_t)(r - 256) * 256
                                 : wv + (size_t)(r - 512) * 256;
    Wall[(size_t)r * 256 + t] = (_Float16)src[t];
  } else {
    int idx = (r - 768) * 256 + t;  // 0..4095
    projh[idx] = (_Float16)proj[idx];
  }
}

// ---------------------------------------------------------------- combine
__global__ __launch_bounds__(256) void combine_w(
    const float* __restrict__ wo, const float* __restrict__ bo,
    const float* __restrict__ wp, const float* __restrict__ bp,
    _Float16* __restrict__ Wc, float* __restrict__ bc) {
  int o = blockIdx.x;
  int cp = threadIdx.x;
  float acc = 0.f;
  for (int c = 0; c < 256; ++c) acc += wp[o * 256 + c] * wo[c * 256 + cp];
  Wc[o * 256 + cp] = (_Float16)acc;
  if (cp == 0) {
    float ab = bp[o];
    for (int c = 0; c < 256; ++c) ab += wp[o * 256 + c] * bo[c];
    bc[o] = ab;
  }
}

// ---------------------------------------------------------------- x transpose fp32 [b][c][n] -> fp16 [b*n][c]
__global__ __launch_bounds__(256) void prep_xT(
    const float* __restrict__ x, _Float16* __restrict__ xT) {
  __shared__ float T_s[64][65];
  int n0 = blockIdx.x * 64, c0 = blockIdx.y * 64, b = blockIdx.z;
  int t = threadIdx.x;
  for (int i = 0; i < 4; ++i) {
    int f = t + i * 256;
    int cc = f >> 4, n4 = f & 15;
    float4 a = *(const float4*)(x + ((size_t)(b * 256 + c0 + cc)) * NTOT + n0 + n4 * 4);
    T_s[cc][n4 * 4 + 0] = a.x;
    T_s[cc][n4 * 4 + 1] = a.y;
    T_s[cc][n4 * 4 + 2] = a.z;
    T_s[cc][n4 * 4 + 3] = a.w;
  }
  __syncthreads();
  for (int i = 0; i < 2; ++i) {
    int f = t + i * 256;
    int nn = f >> 3, c8 = f & 7;
    h8 hv;
    for (int j = 0; j < 8; ++j) hv[j] = (_Float16)T_s[c8 * 8 + j][nn];
    *(h8*)(xT + ((size_t)(b * NTOT + n0 + nn)) * 256 + c0 + c8 * 8) = hv;
  }
}

// ---------------------------------------------------------------- qkv MFMA gemm
__global__ __launch_bounds__(256) void qkv_mfma(
    const _Float16* __restrict__ xT, const _Float16* __restrict__ Wall,
    _Float16* __restrict__ q, _Float16* __restrict__ k, _Float16* __restrict__ v) {
  __shared__ __align__(16) _Float16 A_s[128 * 32];
  __shared__ __align__(16) _Float16 B_s[256 * 32];
  int n0 = blockIdx.x * 128;
  int sel = blockIdx.y;
  _Float16* Out = (sel == 0) ? q : (sel == 1) ? k : v;
  const _Float16* Wb = Wall + (size_t)sel * 256 * 256;
  int t = threadIdx.x;
  int wave = t >> 6, lane = t & 63;
  int wm = (wave & 1) * 64, wn = (wave >> 1) * 128;
  int lm = lane & 15, lg = lane >> 4;
  f4 acc[4][8] = {};
  for (int kt = 0; kt < 8; ++kt) {
    int c0 = kt * 32;
    __syncthreads();
    {
      int row = t >> 2, ch = t & 3;
      const _Float16* g = xT + (size_t)(n0 + row) * 256 + c0 + ch * 8;
      *(h8*)&A_s[row * 32 + ch * 8] = *(const h8*)g;
      *(h8*)&A_s[(row + 64) * 32 + ch * 8] = *(const h8*)(g + 64 * 256);
#pragma unroll
      for (int i = 0; i < 4; ++i) {
        const _Float16* gw = Wb + (size_t)(row + i * 64) * 256 + c0 + ch * 8;
        *(h8*)&B_s[(row + i * 64) * 32 + ch * 8] = *(const h8*)gw;
      }
    }
    __syncthreads();
    h8 a[4], b[8];
#pragma unroll
    for (int mi = 0; mi < 4; ++mi)
      a[mi] = *(const h8*)&A_s[(wm + mi * 16 + lm) * 32 + lg * 8];
#pragma unroll
    for (int ni = 0; ni < 8; ++ni)
      b[ni] = *(const h8*)&B_s[(wn + ni * 16 + lm) * 32 + lg * 8];
#pragma unroll
    for (int mi = 0; mi < 4; ++mi)
#pragma unroll
      for (int ni = 0; ni < 8; ++ni)
        acc[mi][ni] = __builtin_amdgcn_mfma_f32_16x16x32_f16(a[mi], b[ni], acc[mi][ni], 0, 0, 0);
  }
#pragma unroll
  for (int mi = 0; mi < 4; ++mi)
#pragma unroll
    for (int ni = 0; ni < 8; ++ni)
#pragma unroll
      for (int r = 0; r < 4; ++r) {
        int row = n0 + wm + mi * 16 + lg * 4 + r;
        int col = wn + ni * 16 + lm;
        Out[(size_t)row * 256 + col] = (_Float16)acc[mi][ni][r];
      }
}

// ---------------------------------------------------------------- kmax via MFMA
__global__ __launch_bounds__(256) void kmax_mfma(
    const _Float16* __restrict__ k, const _Float16* __restrict__ projh,
    float* __restrict__ kmaxp) {
  __shared__ __align__(16) _Float16 k_s[128 * 36];
  __shared__ float red4[4];
  int bh = blockIdx.y, b = bh >> 3, h = bh & 7;
  int nbase = blockIdx.x * 512;
  int t = threadIdx.x, wave = t >> 6, lane = t & 63, lm = lane & 15, lg = lane >> 4;
  h8 pr[8];
#pragma unroll
  for (int mt = 0; mt < 8; ++mt) pr[mt] = *(const h8*)&projh[(mt * 16 + lm) * 32 + lg * 8];
  float vmax = -1e30f;
  for (int ch = 0; ch < 4; ++ch) {
    int n0 = nbase + ch * 128;
    __syncthreads();
#pragma unroll
    for (int i = 0; i < 2; ++i) {
      int f = t + i * 256;
      int row = f >> 2, c = f & 3;
      *(h8*)&k_s[row * 36 + c * 8] =
          *(const h8*)(k + ((size_t)(b * NTOT + n0 + row)) * 256 + h * 32 + c * 8);
    }
    __syncthreads();
#pragma unroll
    for (int nt = 0; nt < 2; ++nt) {
      h8 a = *(const h8*)&k_s[(wave * 32 + nt * 16 + lm) * 36 + lg * 8];
#pragma unroll
      for (int mt = 0; mt < 8; ++mt) {
        f4 z = {0.f, 0.f, 0.f, 0.f};
        f4 d = __builtin_amdgcn_mfma_f32_16x16x32_f16(a, pr[mt], z, 0, 0, 0);
        vmax = fmaxf(vmax, fmaxf(fmaxf(d[0], d[1]), fmaxf(d[2], d[3])));
      }
    }
  }
  for (int i = 1; i < 64; i <<= 1) vmax = fmaxf(vmax, __shfl_xor(vmax, i, 64));
  if (lane == 0) red4[wave] = vmax;
  __syncthreads();
  if (t == 0)
    kmaxp[bh * 18 + blockIdx.x] =
        NORMC * fmaxf(fmaxf(red4[0], red4[1]), fmaxf(red4[2], red4[3]));
}

// ---------------------------------------------------------------- ctx + ksum via MFMA
// ctx_aug[bh][m][0:32] += kp^T @ v ; ctx_aug[bh][m][32] += sum_n kp
__global__ __launch_bounds__(256) void ctx_mfma(
    const _Float16* __restrict__ k, const _Float16* __restrict__ v,
    const _Float16* __restrict__ projh, const float* __restrict__ kmaxp,
    float* __restrict__ ctx_aug) {
  __shared__ __align__(16) _Float16 k_s[128 * 36];
  __shared__ __align__(16) _Float16 vT_s[32 * 136];
  __shared__ __align__(16) _Float16 kpT[128 * 136];
  __shared__ float tmp_s[256];  // diag per chunk; ksum-red at end
  __shared__ float kmax_sh;
  int bh = blockIdx.y, b = bh >> 3, h = bh & 7;
  int nbase = blockIdx.x * 512;
  int t = threadIdx.x, wave = t >> 6, lane = t & 63, lm = lane & 15, lg = lane >> 4;
  h8 pr[8];
#pragma unroll
  for (int mt = 0; mt < 8; ++mt) pr[mt] = *(const h8*)&projh[(mt * 16 + lm) * 32 + lg * 8];
  if (t == 0) {
    float mx = -1e30f;
    for (int i = 0; i < 18; ++i) mx = fmaxf(mx, kmaxp[bh * 18 + i]);
    kmax_sh = mx;
  }
  __syncthreads();
  float kmax = kmax_sh;
  f4 cacc[2][2] = {};
  float ksacc = 0.f;
  for (int ch = 0; ch < 4; ++ch) {
    int n0 = nbase + ch * 128;
#pragma unroll
    for (int i = 0; i < 2; ++i) {
      int f = t + i * 256;
      int row = f >> 2, c = f & 3;
      size_t gb = ((size_t)(b * NTOT + n0 + row)) * 256 + h * 32 + c * 8;
      *(h8*)&k_s[row * 36 + c * 8] = *(const h8*)(k + gb);
      h8 vv = *(const h8*)(v + gb);
#pragma unroll
      for (int j = 0; j < 8; ++j) vT_s[(c * 8 + j) * 136 + row] = vv[j];
    }
    __syncthreads();
    if (t < 128) {
      float s = 0.f;
#pragma unroll
      for (int c = 0; c < 4; ++c) {
        h8 kv = *(const h8*)&k_s[t * 36 + c * 8];
#pragma unroll
        for (int j = 0; j < 8; ++j) s += (float)kv[j] * (float)kv[j];
      }
      tmp_s[t] = s * (0.5f * NORMC * NORMC);
    }
    f4 dsh[2][8];
#pragma unroll
    for (int nt = 0; nt < 2; ++nt) {
      h8 a = *(const h8*)&k_s[(wave * 32 + nt * 16 + lm) * 36 + lg * 8];
#pragma unroll
      for (int mt = 0; mt < 8; ++mt) {
        f4 z = {0.f, 0.f, 0.f, 0.f};
        dsh[nt][mt] = __builtin_amdgcn_mfma_f32_16x16x32_f16(a, pr[mt], z, 0, 0, 0);
      }
    }
    __syncthreads();
#pragma unroll
    for (int nt = 0; nt < 2; ++nt)
#pragma unroll
      for (int mt = 0; mt < 8; ++mt)
#pragma unroll
        for (int r = 0; r < 4; ++r) {
          int nl = wave * 32 + nt * 16 + lg * 4 + r;
          float val = RATIO * (__expf(NORMC * dsh[nt][mt][r] - tmp_s[nl] - kmax) + FEPS);
          kpT[(mt * 16 + lm) * 136 + nl] = (_Float16)val;
        }
    __syncthreads();
#pragma unroll
    for (int k2 = 0; k2 < 4; ++k2) {
      h8 a2[2], b2[2];
#pragma unroll
      for (int mt2 = 0; mt2 < 2; ++mt2)
        a2[mt2] = *(const h8*)&kpT[(wave * 32 + mt2 * 16 + lm) * 136 + k2 * 32 + lg * 8];
#pragma unroll
      for (int dt = 0; dt < 2; ++dt)
        b2[dt] = *(const h8*)&vT_s[(dt * 16 + lm) * 136 + k2 * 32 + lg * 8];
#pragma unroll
      for (int mt2 = 0; mt2 < 2; ++mt2)
#pragma unroll
        for (int dt = 0; dt < 2; ++dt)
          cacc[mt2][dt] = __builtin_amdgcn_mfma_f32_16x16x32_f16(a2[mt2], b2[dt], cacc[mt2][dt], 0, 0, 0);
    }
    {
      int m = t & 127, half = t >> 7;
#pragma unroll
      for (int j = 0; j < 8; ++j) {
        h8 kv = *(const h8*)&kpT[m * 136 + half * 64 + j * 8];
#pragma unroll
        for (int e = 0; e < 8; ++e) ksacc += (float)kv[e];
      }
    }
    __syncthreads();
  }
  float* cb = ctx_aug + (size_t)bh * 4608;
#pragma unroll
  for (int mt2 = 0; mt2 < 2; ++mt2)
#pragma unroll
    for (int dt = 0; dt < 2; ++dt)
#pragma unroll
      for (int r = 0; r < 4; ++r)
        atomicAdd(&cb[(wave * 32 + mt2 * 16 + lg * 4 + r) * 36 + dt * 16 + lm],
                  cacc[mt2][dt][r]);
  tmp_s[t] = ksacc;
  __syncthreads();
  if (t < 128) atomicAdd(&cb[t * 36 + 32], tmp_s[t] + tmp_s[t + 128]);
}

// ---------------------------------------------------------------- q side via MFMA
__global__ __launch_bounds__(256) void attn_mfma(
    const _Float16* __restrict__ q, const _Float16* __restrict__ projh,
    const float* __restrict__ ctx_aug, _Float16* __restrict__ attn) {
  __shared__ __align__(16) _Float16 q_sh[128 * 36];
  __shared__ __align__(16) _Float16 qp_s[128 * 136];
  __shared__ __align__(16) _Float16 ctxT[32 * 136];
  __shared__ float diag_s[128], den_s[128], ksum_s[128];
  int n0 = blockIdx.x * 128;
  int yb = blockIdx.y;
  int b = yb >> 1, hg = yb & 1;
  int t = threadIdx.x, wave = t >> 6, lane = t & 63, lm = lane & 15, lg = lane >> 4;
  h8 pr[8];
#pragma unroll
  for (int mt = 0; mt < 8; ++mt) pr[mt] = *(const h8*)&projh[(mt * 16 + lm) * 32 + lg * 8];
  for (int h = hg * 4; h < hg * 4 + 4; ++h) {
    int bh = b * 8 + h;
    const float* cb = ctx_aug + (size_t)bh * 4608;
#pragma unroll
    for (int i = 0; i < 2; ++i) {
      int f = t + i * 256;
      int row = f >> 2, c = f & 3;
      *(h8*)&q_sh[row * 36 + c * 8] =
          *(const h8*)(q + ((size_t)(b * NTOT + n0 + row)) * 256 + h * 32 + c * 8);
    }
    {
      int m = t >> 1, dbase = (t & 1) * 16;
#pragma unroll
      for (int g = 0; g < 4; ++g) {
        float4 cv = *(const float4*)(cb + m * 36 + dbase + g * 4);
        ctxT[(dbase + g * 4 + 0) * 136 + m] = (_Float16)cv.x;
        ctxT[(dbase + g * 4 + 1) * 136 + m] = (_Float16)cv.y;
        ctxT[(dbase + g * 4 + 2) * 136 + m] = (_Float16)cv.z;
        ctxT[(dbase + g * 4 + 3) * 136 + m] = (_Float16)cv.w;
      }
    }
    if (t < 128) ksum_s[t] = cb[t * 36 + 32];
    __syncthreads();
    if (t < 128) {
      float s = 0.f;
#pragma unroll
      for (int c = 0; c < 4; ++c) {
        h8 qv = *(const h8*)&q_sh[t * 36 + c * 8];
#pragma unroll
        for (int j = 0; j < 8; ++j) s += (float)qv[j] * (float)qv[j];
      }
      diag_s[t] = s * (0.5f * NORMC * NORMC);
    }
    f4 dsh[2][8];
#pragma unroll
    for (int nt = 0; nt < 2; ++nt) {
      h8 a = *(const h8*)&q_sh[(wave * 32 + nt * 16 + lm) * 36 + lg * 8];
#pragma unroll
      for (int mt = 0; mt < 8; ++mt) {
        f4 z = {0.f, 0.f, 0.f, 0.f};
        dsh[nt][mt] = __builtin_amdgcn_mfma_f32_16x16x32_f16(a, pr[mt], z, 0, 0, 0);
      }
    }
    __syncthreads();
#pragma unroll
    for (int nt = 0; nt < 2; ++nt) {
      float mx[4];
#pragma unroll
      for (int r = 0; r < 4; ++r) {
        float m0 = -1e30f;
#pragma unroll
        for (int mt = 0; mt < 8; ++mt) m0 = fmaxf(m0, dsh[nt][mt][r]);
        for (int i = 1; i < 16; i <<= 1) m0 = fmaxf(m0, __shfl_xor(m0, i, 64));
        mx[r] = m0;
      }
#pragma unroll
      for (int mt = 0; mt < 8; ++mt)
#pragma unroll
        for (int r = 0; r < 4; ++r) {
          int nl = wave * 32 + nt * 16 + lg * 4 + r;
          float val =
              RATIO * (__expf(NORMC * dsh[nt][mt][r] - diag_s[nl] - NORMC * mx[r]) + FEPS);
          qp_s[nl * 136 + mt * 16 + lm] = (_Float16)val;
        }
    }
    __syncthreads();
    if (t < 128) {
      float s = 0.f;
#pragma unroll
      for (int j = 0; j < 16; ++j) {
        h8 qv = *(const h8*)&qp_s[t * 136 + j * 8];
#pragma unroll
        for (int e = 0; e < 8; ++e) s += (float)qv[e] * ksum_s[j * 8 + e];
      }
      den_s[t] = 1.f / s;
    }
    f4 oacc[2][2] = {};
#pragma unroll
    for (int k2 = 0; k2 < 4; ++k2) {
      h8 a2[2], b2[2];
#pragma unroll
      for (int nt = 0; nt < 2; ++nt)
        a2[nt] = *(const h8*)&qp_s[(wave * 32 + nt * 16 + lm) * 136 + k2 * 32 + lg * 8];
#pragma unroll
      for (int dt = 0; dt < 2; ++dt)
        b2[dt] = *(const h8*)&ctxT[(dt * 16 + lm) * 136 + k2 * 32 + lg * 8];
#pragma unroll
      for (int nt = 0; nt < 2; ++nt)
#pragma unroll
        for (int dt = 0; dt < 2; ++dt)
          oacc[nt][dt] = __builtin_amdgcn_mfma_f32_16x16x32_f16(a2[nt], b2[dt], oacc[nt][dt], 0, 0, 0);
    }
    __syncthreads();
#pragma unroll
    for (int nt = 0; nt < 2; ++nt)
#pragma unroll
      for (int dt = 0; dt < 2; ++dt)
#pragma unroll
        for (int r = 0; r < 4; ++r) {
          int nl = wave * 32 + nt * 16 + lg * 4 + r;
          float di = den_s[nl];
          attn[((size_t)(b * NTOT + n0 + nl)) * 256 + h * 32 + dt * 16 + lm] =
              (_Float16)(oacc[nt][dt][r] * di);
        }
  }
}

// ---------------------------------------------------------------- output MFMA gemm
__global__ __launch_bounds__(256) void out_mfma(
    const _Float16* __restrict__ Wc, const _Float16* __restrict__ attn,
    const float* __restrict__ bc, float* __restrict__ out) {
  __shared__ __align__(16) _Float16 A_s[128 * 32];
  __shared__ __align__(16) _Float16 B_s[256 * 32];
  int n0 = blockIdx.x * 256;
  int o0 = blockIdx.y * 128;
  int b = n0 / NTOT;
  int nb0 = n0 - b * NTOT;
  int t = threadIdx.x;
  int wave = t >> 6, lane = t & 63;
  int wm = (wave & 1) * 64, wn = (wave >> 1) * 128;
  int lm = lane & 15, lg = lane >> 4;
  f4 acc[4][8] = {};
  for (int kt = 0; kt < 8; ++kt) {
    int c0 = kt * 32;
    __syncthreads();
    {
      int row = t >> 2, ch = t & 3;
      const _Float16* ga = Wc + (size_t)(o0 + row) * 256 + c0 + ch * 8;
      *(h8*)&A_s[row * 32 + ch * 8] = *(const h8*)ga;
      *(h8*)&A_s[(row + 64) * 32 + ch * 8] = *(const h8*)(ga + 64 * 256);
#pragma unroll
      for (int i = 0; i < 4; ++i) {
        const _Float16* gb = attn + (size_t)(n0 + row + i * 64) * 256 + c0 + ch * 8;
        *(h8*)&B_s[(row + i * 64) * 32 + ch * 8] = *(const h8*)gb;
      }
    }
    __syncthreads();
    h8 a[4], b8[8];
#pragma unroll
    for (int mi = 0; mi < 4; ++mi)
      a[mi] = *(const h8*)&A_s[(wm + mi * 16 + lm) * 32 + lg * 8];
#pragma unroll
    for (int ni = 0; ni < 8; ++ni)
      b8[ni] = *(const h8*)&B_s[(wn + ni * 16 + lm) * 32 + lg * 8];
#pragma unroll
    for (int mi = 0; mi < 4; ++mi)
#pragma unroll
      for (int ni = 0; ni < 8; ++ni)
        acc[mi][ni] = __builtin_amdgcn_mfma_f32_16x16x32_f16(a[mi], b8[ni], acc[mi][ni], 0, 0, 0);
  }
  float bias[4][4];
#pragma unroll
  for (int mi = 0; mi < 4; ++mi)
#pragma unroll
    for (int r = 0; r < 4; ++r)
      bias[mi][r] = bc[o0 + wm + mi * 16 + lg * 4 + r];
#pragma unroll
  for (int mi = 0; mi < 4; ++mi)
#pragma unroll
    for (int ni = 0; ni < 8; ++ni)
#pragma unroll
      for (int r = 0; r < 4; ++r) {
        int o = o0 + wm + mi * 16 + lg * 4 + r;
        int n = nb0 + wn + ni * 16 + lm;
        out[((size_t)(b * 256 + o)) * NTOT + n] = acc[mi][ni][r] + bias[mi][r];
      }
}

// ---------------------------------------------------------------- launch
extern "C" void kernel_launch(void* const* d_in, const int* in_sizes, int n_in,
                              void* d_out, int out_size, void* d_ws, size_t ws_size,
                              hipStream_t stream) {
  const float* x = (const float*)d_in[0];
  const float* wq = (const float*)d_in[1];
  const float* wk = (const float*)d_in[2];
  const float* wv = (const float*)d_in[3];
  const float* wo = (const float*)d_in[4];
  const float* bo = (const float*)d_in[5];
  const float* proj = (const float*)d_in[6];
  const float* wp = (const float*)d_in[7];
  const float* bp = (const float*)d_in[8];
  float* out = (float*)d_out;
  float* ws = (float*)d_ws;

  float* ctx_aug = ws;                  // 32*128*36 = 147456
  float* kmaxp = ctx_aug + 147456;      // 32*18 = 576
  float* bc = kmaxp + 576;              // 256
  _Float16* hb = (_Float16*)(bc + 256);
  const size_t THALF = (size_t)4 * NTOT * 256;  // 9,437,184
  _Float16* q_h = hb;
  _Float16* k_h = q_h + THALF;
  _Float16* v_h = k_h + THALF;
  _Float16* xT = v_h + THALF;          // reused as attn fp16 output
  _Float16* Wall = xT + THALF;         // 768*256
  _Float16* Wc = Wall + 768 * 256;     // 256*256
  _Float16* projh = Wc + 65536;        // 128*32

  hipMemsetAsync(ctx_aug, 0, 147456 * sizeof(float), stream);
  conv_w<<<784, 256, 0, stream>>>(wq, wk, wv, proj, Wall, projh);
  combine_w<<<256, 256, 0, stream>>>(wo, bo, wp, bp, Wc, bc);
  prep_xT<<<dim3(144, 4, 4), 256, 0, stream>>>(x, xT);
  qkv_mfma<<<dim3(288, 3), 256, 0, stream>>>(xT, Wall, q_h, k_h, v_h);
  kmax_mfma<<<dim3(18, 32), 256, 0, stream>>>(k_h, projh, kmaxp);
  ctx_mfma<<<dim3(18, 32), 256, 0, stream>>>(k_h, v_h, projh, kmaxp, ctx_aug);
  attn_mfma<<<dim3(72, 8), 256, 0, stream>>>(q_h, projh, ctx_aug, xT);
  out_mfma<<<dim3(144, 2), 256, 0, stream>>>(Wc, xT, bc, out);
}

// Round 4
// 222.627 us; speedup vs baseline: 3.2804x; 1.2273x over previous
//
#include <hip/hip_runtime.h>

#define NTOT 9216
#define NORMC 0.42044820762685725f   /* 32^-0.25 */
#define RATIO 0.08838834764831845f   /* 128^-0.5 */
#define FEPS 1e-4f

typedef _Float16 h8 __attribute__((ext_vector_type(8)));
typedef float f4 __attribute__((ext_vector_type(4)));

// async global->LDS, 16B per lane; lds dest = wave-uniform base + lane*16
__device__ __forceinline__ void gld16(const _Float16* g, _Float16* l) {
  __builtin_amdgcn_global_load_lds((const __attribute__((address_space(1))) void*)g,
                                   (__attribute__((address_space(3))) void*)l, 16, 0, 0);
}

// ---------------------------------------------------------------- small prep (fused)
__global__ __launch_bounds__(256) void prep_small(
    const float* __restrict__ wq, const float* __restrict__ wk,
    const float* __restrict__ wv, const float* __restrict__ proj,
    const float* __restrict__ wo, const float* __restrict__ bo,
    const float* __restrict__ wp, const float* __restrict__ bp,
    _Float16* __restrict__ Wall, _Float16* __restrict__ projh,
    _Float16* __restrict__ Wc, float* __restrict__ bc) {
  int r = blockIdx.x, t = threadIdx.x;
  if (r < 768) {
    const float* src = (r < 256) ? wq + (size_t)r * 256
                     : (r < 512) ? wk + (size_t)(r - 256) * 256
                                 : wv + (size_t)(r - 512) * 256;
    Wall[(size_t)r * 256 + t] = (_Float16)src[t];
  } else if (r < 784) {
    int idx = (r - 768) * 256 + t;
    projh[idx] = (_Float16)proj[idx];
  } else {
    int o = r - 784;
    float acc = 0.f;
    for (int c = 0; c < 256; ++c) acc += wp[o * 256 + c] * wo[c * 256 + t];
    Wc[o * 256 + t] = (_Float16)acc;
    if (t == 0) {
      float ab = bp[o];
      for (int c = 0; c < 256; ++c) ab += wp[o * 256 + c] * bo[c];
      bc[o] = ab;
    }
  }
}

// ---------------------------------------------------------------- x transpose fp32 [b][c][n] -> fp16 [b*n][c]
__global__ __launch_bounds__(256) void prep_xT(
    const float* __restrict__ x, _Float16* __restrict__ xT) {
  __shared__ float T_s[64][65];
  int n0 = blockIdx.x * 64, c0 = blockIdx.y * 64, b = blockIdx.z;
  int t = threadIdx.x;
  for (int i = 0; i < 4; ++i) {
    int f = t + i * 256;
    int cc = f >> 4, n4 = f & 15;
    float4 a = *(const float4*)(x + ((size_t)(b * 256 + c0 + cc)) * NTOT + n0 + n4 * 4);
    T_s[cc][n4 * 4 + 0] = a.x;
    T_s[cc][n4 * 4 + 1] = a.y;
    T_s[cc][n4 * 4 + 2] = a.z;
    T_s[cc][n4 * 4 + 3] = a.w;
  }
  __syncthreads();
  for (int i = 0; i < 2; ++i) {
    int f = t + i * 256;
    int nn = f >> 3, c8 = f & 7;
    h8 hv;
    for (int j = 0; j < 8; ++j) hv[j] = (_Float16)T_s[c8 * 8 + j][nn];
    *(h8*)(xT + ((size_t)(b * NTOT + n0 + nn)) * 256 + c0 + c8 * 8) = hv;
  }
}

// ---------------------------------------------------------------- qkv MFMA gemm (m97-style)
__global__ __launch_bounds__(256) void qkv_mfma(
    const _Float16* __restrict__ xT, const _Float16* __restrict__ Wall,
    _Float16* __restrict__ q, _Float16* __restrict__ k, _Float16* __restrict__ v) {
  __shared__ __align__(16) _Float16 A_s[128 * 32];
  __shared__ __align__(16) _Float16 B_s[128 * 32];
  int n0 = blockIdx.x * 128;
  int co0 = blockIdx.y * 128;
  int sel = blockIdx.z;
  _Float16* Out = (sel == 0) ? q : (sel == 1) ? k : v;
  const _Float16* Wb = Wall + (size_t)sel * 65536;
  int t = threadIdx.x, wave = t >> 6, lane = t & 63;
  int lm = lane & 15, lg = lane >> 4;
  int wm = (wave & 1) * 64, wn = (wave >> 1) * 64;
  const _Float16* gA = xT + (size_t)(n0 + wave * 32 + (lane >> 2)) * 256 + (lane & 3) * 8;
  const _Float16* gB = Wb + (size_t)(co0 + wave * 32 + (lane >> 2)) * 256 + (lane & 3) * 8;
  _Float16* lA = A_s + wave * 1024;
  _Float16* lB = B_s + wave * 1024;
  f4 acc[4][4] = {};
  for (int kt = 0; kt < 8; ++kt) {
    int c0 = kt * 32;
    __syncthreads();
    gld16(gA + c0, lA);
    gld16(gA + c0 + 16 * 256, lA + 512);
    gld16(gB + c0, lB);
    gld16(gB + c0 + 16 * 256, lB + 512);
    __syncthreads();
    h8 a[4], bf[4];
#pragma unroll
    for (int mi = 0; mi < 4; ++mi) a[mi] = *(const h8*)&A_s[(wm + mi * 16 + lm) * 32 + lg * 8];
#pragma unroll
    for (int ni = 0; ni < 4; ++ni) bf[ni] = *(const h8*)&B_s[(wn + ni * 16 + lm) * 32 + lg * 8];
#pragma unroll
    for (int mi = 0; mi < 4; ++mi)
#pragma unroll
      for (int ni = 0; ni < 4; ++ni)
        acc[mi][ni] = __builtin_amdgcn_mfma_f32_16x16x32_f16(a[mi], bf[ni], acc[mi][ni], 0, 0, 0);
  }
#pragma unroll
  for (int mi = 0; mi < 4; ++mi)
#pragma unroll
    for (int ni = 0; ni < 4; ++ni)
#pragma unroll
      for (int r = 0; r < 4; ++r)
        Out[(size_t)(n0 + wm + mi * 16 + lg * 4 + r) * 256 + co0 + wn + ni * 16 + lm] =
            (_Float16)acc[mi][ni][r];
}

// ---------------------------------------------------------------- kmax via MFMA (+ctx_aug zeroing)
__global__ __launch_bounds__(256) void kmax_mfma(
    const _Float16* __restrict__ k, const _Float16* __restrict__ projh,
    float* __restrict__ kmaxp, float* __restrict__ ctx_aug) {
  __shared__ __align__(16) _Float16 k_s[128 * 32];
  __shared__ float red4[4];
  int bh = blockIdx.y, b = bh >> 3, h = bh & 7;
  int nbase = blockIdx.x * 512;
  int t = threadIdx.x, wave = t >> 6, lane = t & 63, lm = lane & 15, lg = lane >> 4;
  if (blockIdx.x == 0) {
#pragma unroll
    for (int i = 0; i < 18; ++i) ctx_aug[(size_t)bh * 4608 + t + i * 256] = 0.f;
  }
  h8 pr[8];
#pragma unroll
  for (int mt = 0; mt < 8; ++mt) pr[mt] = *(const h8*)&projh[(mt * 16 + lm) * 32 + lg * 8];
  const _Float16* gK =
      k + ((size_t)(b * NTOT + nbase + wave * 32 + (lane >> 2))) * 256 + h * 32 + (lane & 3) * 8;
  _Float16* lK = k_s + wave * 1024;
  float vmax = -1e30f;
  for (int ch = 0; ch < 4; ++ch) {
    __syncthreads();
    gld16(gK + (size_t)ch * 128 * 256, lK);
    gld16(gK + (size_t)ch * 128 * 256 + 16 * 256, lK + 512);
    __syncthreads();
#pragma unroll
    for (int nt = 0; nt < 2; ++nt) {
      h8 a = *(const h8*)&k_s[(wave * 32 + nt * 16 + lm) * 32 + lg * 8];
#pragma unroll
      for (int mt = 0; mt < 8; ++mt) {
        f4 z = {0.f, 0.f, 0.f, 0.f};
        f4 d = __builtin_amdgcn_mfma_f32_16x16x32_f16(a, pr[mt], z, 0, 0, 0);
        vmax = fmaxf(vmax, fmaxf(fmaxf(d[0], d[1]), fmaxf(d[2], d[3])));
      }
    }
  }
  for (int i = 1; i < 64; i <<= 1) vmax = fmaxf(vmax, __shfl_xor(vmax, i, 64));
  if (lane == 0) red4[wave] = vmax;
  __syncthreads();
  if (t == 0)
    kmaxp[bh * 18 + blockIdx.x] =
        NORMC * fmaxf(fmaxf(red4[0], red4[1]), fmaxf(red4[2], red4[3]));
}

// ---------------------------------------------------------------- ctx + ksum via MFMA
__global__ __launch_bounds__(256) void ctx_mfma(
    const _Float16* __restrict__ k, const _Float16* __restrict__ v,
    const _Float16* __restrict__ projh, const float* __restrict__ kmaxp,
    float* __restrict__ ctx_aug) {
  __shared__ __align__(16) _Float16 k_s[128 * 32];
  __shared__ __align__(16) _Float16 vT_s[32 * 136];
  __shared__ __align__(16) _Float16 kpT[128 * 136];
  __shared__ float tmp_s[256];
  __shared__ float kmax_sh;
  int bh = blockIdx.y, b = bh >> 3, h = bh & 7;
  int nbase = blockIdx.x * 512;
  int t = threadIdx.x, wave = t >> 6, lane = t & 63, lm = lane & 15, lg = lane >> 4;
  h8 pr[8];
#pragma unroll
  for (int mt = 0; mt < 8; ++mt) pr[mt] = *(const h8*)&projh[(mt * 16 + lm) * 32 + lg * 8];
  if (t == 0) {
    float mx = -1e30f;
    for (int i = 0; i < 18; ++i) mx = fmaxf(mx, kmaxp[bh * 18 + i]);
    kmax_sh = mx;
  }
  __syncthreads();
  float kmax = kmax_sh;
  const _Float16* gK =
      k + ((size_t)(b * NTOT + nbase + wave * 32 + (lane >> 2))) * 256 + h * 32 + (lane & 3) * 8;
  _Float16* lK = k_s + wave * 1024;
  f4 cacc[2][2] = {};
  float ksacc = 0.f;
  for (int ch = 0; ch < 4; ++ch) {
    int n0 = nbase + ch * 128;
    gld16(gK + (size_t)ch * 128 * 256, lK);
    gld16(gK + (size_t)ch * 128 * 256 + 16 * 256, lK + 512);
#pragma unroll
    for (int i = 0; i < 2; ++i) {
      int f = t + i * 256;
      int row = f >> 2, c = f & 3;
      h8 vv = *(const h8*)(v + ((size_t)(b * NTOT + n0 + row)) * 256 + h * 32 + c * 8);
#pragma unroll
      for (int j = 0; j < 8; ++j) vT_s[(c * 8 + j) * 136 + row] = vv[j];
    }
    __syncthreads();
    if (t < 128) {
      float s = 0.f;
#pragma unroll
      for (int c = 0; c < 4; ++c) {
        h8 kv = *(const h8*)&k_s[t * 32 + c * 8];
#pragma unroll
        for (int j = 0; j < 8; ++j) s += (float)kv[j] * (float)kv[j];
      }
      tmp_s[t] = s * (0.5f * NORMC * NORMC);
    }
    f4 dsh[2][8];
#pragma unroll
    for (int nt = 0; nt < 2; ++nt) {
      h8 a = *(const h8*)&k_s[(wave * 32 + nt * 16 + lm) * 32 + lg * 8];
#pragma unroll
      for (int mt = 0; mt < 8; ++mt) {
        f4 z = {0.f, 0.f, 0.f, 0.f};
        dsh[nt][mt] = __builtin_amdgcn_mfma_f32_16x16x32_f16(a, pr[mt], z, 0, 0, 0);
      }
    }
    __syncthreads();
#pragma unroll
    for (int nt = 0; nt < 2; ++nt)
#pragma unroll
      for (int mt = 0; mt < 8; ++mt)
#pragma unroll
        for (int r = 0; r < 4; ++r) {
          int nl = wave * 32 + nt * 16 + lg * 4 + r;
          float val = RATIO * (__expf(NORMC * dsh[nt][mt][r] - tmp_s[nl] - kmax) + FEPS);
          kpT[(mt * 16 + lm) * 136 + nl] = (_Float16)val;
        }
    __syncthreads();
#pragma unroll
    for (int k2 = 0; k2 < 4; ++k2) {
      h8 a2[2], b2[2];
#pragma unroll
      for (int mt2 = 0; mt2 < 2; ++mt2)
        a2[mt2] = *(const h8*)&kpT[(wave * 32 + mt2 * 16 + lm) * 136 + k2 * 32 + lg * 8];
#pragma unroll
      for (int dt = 0; dt < 2; ++dt)
        b2[dt] = *(const h8*)&vT_s[(dt * 16 + lm) * 136 + k2 * 32 + lg * 8];
#pragma unroll
      for (int mt2 = 0; mt2 < 2; ++mt2)
#pragma unroll
        for (int dt = 0; dt < 2; ++dt)
          cacc[mt2][dt] =
              __builtin_amdgcn_mfma_f32_16x16x32_f16(a2[mt2], b2[dt], cacc[mt2][dt], 0, 0, 0);
    }
    {
      int m = t & 127, half = t >> 7;
#pragma unroll
      for (int j = 0; j < 8; ++j) {
        h8 kv = *(const h8*)&kpT[m * 136 + half * 64 + j * 8];
#pragma unroll
        for (int e = 0; e < 8; ++e) ksacc += (float)kv[e];
      }
    }
    __syncthreads();
  }
  float* cb = ctx_aug + (size_t)bh * 4608;
#pragma unroll
  for (int mt2 = 0; mt2 < 2; ++mt2)
#pragma unroll
    for (int dt = 0; dt < 2; ++dt)
#pragma unroll
      for (int r = 0; r < 4; ++r)
        atomicAdd(&cb[(wave * 32 + mt2 * 16 + lg * 4 + r) * 36 + dt * 16 + lm],
                  cacc[mt2][dt][r]);
  tmp_s[t] = ksacc;
  __syncthreads();
  if (t < 128) atomicAdd(&cb[t * 36 + 32], tmp_s[t] + tmp_s[t + 128]);
}

// ---------------------------------------------------------------- q side via MFMA (one bh,ntile per block)
__global__ __launch_bounds__(256) void attn_mfma(
    const _Float16* __restrict__ q, const _Float16* __restrict__ projh,
    const float* __restrict__ ctx_aug, _Float16* __restrict__ attn) {
  __shared__ __align__(16) _Float16 q_sh[128 * 32];
  __shared__ __align__(16) _Float16 qp_s[128 * 136];
  __shared__ __align__(16) _Float16 ctxT[32 * 136];
  __shared__ float diag_s[128], den_s[128], ksum_s[128];
  int n0 = blockIdx.x * 128;
  int bh = blockIdx.y, b = bh >> 3, h = bh & 7;
  int t = threadIdx.x, wave = t >> 6, lane = t & 63, lm = lane & 15, lg = lane >> 4;
  const float* cb = ctx_aug + (size_t)bh * 4608;
  h8 pr[8];
#pragma unroll
  for (int mt = 0; mt < 8; ++mt) pr[mt] = *(const h8*)&projh[(mt * 16 + lm) * 32 + lg * 8];
  const _Float16* gQ =
      q + ((size_t)(b * NTOT + n0 + wave * 32 + (lane >> 2))) * 256 + h * 32 + (lane & 3) * 8;
  gld16(gQ, q_sh + wave * 1024);
  gld16(gQ + 16 * 256, q_sh + wave * 1024 + 512);
  {
    int m = t >> 1, dbase = (t & 1) * 16;
#pragma unroll
    for (int g = 0; g < 4; ++g) {
      float4 cv = *(const float4*)(cb + m * 36 + dbase + g * 4);
      ctxT[(dbase + g * 4 + 0) * 136 + m] = (_Float16)cv.x;
      ctxT[(dbase + g * 4 + 1) * 136 + m] = (_Float16)cv.y;
      ctxT[(dbase + g * 4 + 2) * 136 + m] = (_Float16)cv.z;
      ctxT[(dbase + g * 4 + 3) * 136 + m] = (_Float16)cv.w;
    }
  }
  if (t < 128) ksum_s[t] = cb[t * 36 + 32];
  __syncthreads();
  if (t < 128) {
    float s = 0.f;
#pragma unroll
    for (int c = 0; c < 4; ++c) {
      h8 qv = *(const h8*)&q_sh[t * 32 + c * 8];
#pragma unroll
      for (int j = 0; j < 8; ++j) s += (float)qv[j] * (float)qv[j];
    }
    diag_s[t] = s * (0.5f * NORMC * NORMC);
  }
  f4 dsh[2][8];
#pragma unroll
  for (int nt = 0; nt < 2; ++nt) {
    h8 a = *(const h8*)&q_sh[(wave * 32 + nt * 16 + lm) * 32 + lg * 8];
#pragma unroll
    for (int mt = 0; mt < 8; ++mt) {
      f4 z = {0.f, 0.f, 0.f, 0.f};
      dsh[nt][mt] = __builtin_amdgcn_mfma_f32_16x16x32_f16(a, pr[mt], z, 0, 0, 0);
    }
  }
  __syncthreads();
#pragma unroll
  for (int nt = 0; nt < 2; ++nt) {
    float mx[4];
#pragma unroll
    for (int r = 0; r < 4; ++r) {
      float m0 = -1e30f;
#pragma unroll
      for (int mt = 0; mt < 8; ++mt) m0 = fmaxf(m0, dsh[nt][mt][r]);
      for (int i = 1; i < 16; i <<= 1) m0 = fmaxf(m0, __shfl_xor(m0, i, 64));
      mx[r] = m0;
    }
#pragma unroll
    for (int mt = 0; mt < 8; ++mt)
#pragma unroll
      for (int r = 0; r < 4; ++r) {
        int nl = wave * 32 + nt * 16 + lg * 4 + r;
        float val =
            RATIO * (__expf(NORMC * dsh[nt][mt][r] - diag_s[nl] - NORMC * mx[r]) + FEPS);
        qp_s[nl * 136 + mt * 16 + lm] = (_Float16)val;
      }
  }
  __syncthreads();
  if (t < 128) {
    float s = 0.f;
#pragma unroll
    for (int j = 0; j < 16; ++j) {
      h8 qv = *(const h8*)&qp_s[t * 136 + j * 8];
#pragma unroll
      for (int e = 0; e < 8; ++e) s += (float)qv[e] * ksum_s[j * 8 + e];
    }
    den_s[t] = 1.f / s;
  }
  f4 oacc[2][2] = {};
#pragma unroll
  for (int k2 = 0; k2 < 4; ++k2) {
    h8 a2[2], b2[2];
#pragma unroll
    for (int nt = 0; nt < 2; ++nt)
      a2[nt] = *(const h8*)&qp_s[(wave * 32 + nt * 16 + lm) * 136 + k2 * 32 + lg * 8];
#pragma unroll
    for (int dt = 0; dt < 2; ++dt)
      b2[dt] = *(const h8*)&ctxT[(dt * 16 + lm) * 136 + k2 * 32 + lg * 8];
#pragma unroll
    for (int nt = 0; nt < 2; ++nt)
#pragma unroll
      for (int dt = 0; dt < 2; ++dt)
        oacc[nt][dt] = __builtin_amdgcn_mfma_f32_16x16x32_f16(a2[nt], b2[dt], oacc[nt][dt], 0, 0, 0);
  }
  __syncthreads();
#pragma unroll
  for (int nt = 0; nt < 2; ++nt)
#pragma unroll
    for (int dt = 0; dt < 2; ++dt)
#pragma unroll
      for (int r = 0; r < 4; ++r) {
        int nl = wave * 32 + nt * 16 + lg * 4 + r;
        float di = den_s[nl];
        attn[((size_t)(b * NTOT + n0 + nl)) * 256 + h * 32 + dt * 16 + lm] =
            (_Float16)(oacc[nt][dt][r] * di);
      }
}

// ---------------------------------------------------------------- output MFMA gemm (m97-style)
__global__ __launch_bounds__(256) void out_mfma(
    const _Float16* __restrict__ Wc, const _Float16* __restrict__ attn,
    const float* __restrict__ bc, float* __restrict__ out) {
  __shared__ __align__(16) _Float16 A_s[128 * 32];
  __shared__ __align__(16) _Float16 B_s[128 * 32];
  int bx = blockIdx.x;
  int o0 = blockIdx.y * 128;
  int b = bx / 72, nb0 = (bx % 72) * 128;
  int t = threadIdx.x, wave = t >> 6, lane = t & 63;
  int lm = lane & 15, lg = lane >> 4;
  int wm = (wave & 1) * 64, wn = (wave >> 1) * 64;
  const _Float16* gA = Wc + (size_t)(o0 + wave * 32 + (lane >> 2)) * 256 + (lane & 3) * 8;
  const _Float16* gB =
      attn + (size_t)(b * NTOT + nb0 + wave * 32 + (lane >> 2)) * 256 + (lane & 3) * 8;
  _Float16* lA = A_s + wave * 1024;
  _Float16* lB = B_s + wave * 1024;
  f4 acc[4][4] = {};
  for (int kt = 0; kt < 8; ++kt) {
    int c0 = kt * 32;
    __syncthreads();
    gld16(gA + c0, lA);
    gld16(gA + c0 + 16 * 256, lA + 512);
    gld16(gB + c0, lB);
    gld16(gB + c0 + 16 * 256, lB + 512);
    __syncthreads();
    h8 a[4], bf[4];
#pragma unroll
    for (int mi = 0; mi < 4; ++mi) a[mi] = *(const h8*)&A_s[(wm + mi * 16 + lm) * 32 + lg * 8];
#pragma unroll
    for (int ni = 0; ni < 4; ++ni) bf[ni] = *(const h8*)&B_s[(wn + ni * 16 + lm) * 32 + lg * 8];
#pragma unroll
    for (int mi = 0; mi < 4; ++mi)
#pragma unroll
      for (int ni = 0; ni < 4; ++ni)
        acc[mi][ni] = __builtin_amdgcn_mfma_f32_16x16x32_f16(a[mi], bf[ni], acc[mi][ni], 0, 0, 0);
  }
  float bias[4][4];
#pragma unroll
  for (int mi = 0; mi < 4; ++mi)
#pragma unroll
    for (int r = 0; r < 4; ++r) bias[mi][r] = bc[o0 + wm + mi * 16 + lg * 4 + r];
#pragma unroll
  for (int mi = 0; mi < 4; ++mi)
#pragma unroll
    for (int ni = 0; ni < 4; ++ni)
#pragma unroll
      for (int r = 0; r < 4; ++r) {
        int o = o0 + wm + mi * 16 + lg * 4 + r;
        int n = nb0 + wn + ni * 16 + lm;
        out[((size_t)(b * 256 + o)) * NTOT + n] = acc[mi][ni][r] + bias[mi][r];
      }
}

// ---------------------------------------------------------------- launch
extern "C" void kernel_launch(void* const* d_in, const int* in_sizes, int n_in,
                              void* d_out, int out_size, void* d_ws, size_t ws_size,
                              hipStream_t stream) {
  const float* x = (const float*)d_in[0];
  const float* wq = (const float*)d_in[1];
  const float* wk = (const float*)d_in[2];
  const float* wv = (const float*)d_in[3];
  const float* wo = (const float*)d_in[4];
  const float* bo = (const float*)d_in[5];
  const float* proj = (const float*)d_in[6];
  const float* wp = (const float*)d_in[7];
  const float* bp = (const float*)d_in[8];
  float* out = (float*)d_out;
  float* ws = (float*)d_ws;

  float* ctx_aug = ws;                  // 32*128*36 = 147456
  float* kmaxp = ctx_aug + 147456;      // 32*18 = 576
  float* bc = kmaxp + 576;              // 256
  _Float16* hb = (_Float16*)(bc + 256);
  const size_t THALF = (size_t)4 * NTOT * 256;  // 9,437,184
  _Float16* q_h = hb;
  _Float16* k_h = q_h + THALF;
  _Float16* v_h = k_h + THALF;
  _Float16* xT = v_h + THALF;          // reused as attn fp16 output
  _Float16* Wall = xT + THALF;         // 768*256
  _Float16* Wc = Wall + 768 * 256;     // 256*256
  _Float16* projh = Wc + 65536;        // 128*32

  prep_small<<<1040, 256, 0, stream>>>(wq, wk, wv, proj, wo, bo, wp, bp, Wall, projh, Wc, bc);
  prep_xT<<<dim3(144, 4, 4), 256, 0, stream>>>(x, xT);
  qkv_mfma<<<dim3(288, 2, 3), 256, 0, stream>>>(xT, Wall, q_h, k_h, v_h);
  kmax_mfma<<<dim3(18, 32), 256, 0, stream>>>(k_h, projh, kmaxp, ctx_aug);
  ctx_mfma<<<dim3(18, 32), 256, 0, stream>>>(k_h, v_h, projh, kmaxp, ctx_aug);
  attn_mfma<<<dim3(72, 32), 256, 0, stream>>>(q_h, projh, ctx_aug, xT);
  out_mfma<<<dim3(288, 2), 256, 0, stream>>>(Wc, xT, bc, out);
}